// Round 3
// baseline (136.198 us; speedup 1.0000x reference)
//
#include <hip/hip_runtime.h>
#include <cstdint>

#define NB1 8192
#define NB2 8192
#define DDIM 128
#define KROW 256           // stored row: [hi(128) | lo(128)] f16
#define NSTEP 12           // virtual K = 384 (hi*hi + lo*hi + hi*lo), 32 f16/step

using half8    = __attribute__((ext_vector_type(8))) _Float16;
using half4    = __attribute__((ext_vector_type(4))) _Float16;
using float16v = __attribute__((ext_vector_type(16))) float;

typedef __attribute__((address_space(3))) void       lds_void;
typedef const __attribute__((address_space(1))) void glb_void;

__device__ inline unsigned long long packkey(float v, int j) {
  unsigned u = __float_as_uint(v);
  u = (u & 0x80000000u) ? ~u : (u | 0x80000000u);  // monotone float->uint
  return ((unsigned long long)u << 32) | (unsigned)j;
}

// virtual kt -> source 32-f16 chunk index within the [hi|lo] row
__device__ __forceinline__ int a_src(int kt) { return (kt < 8) ? kt : kt - 8; } // hi,lo,hi
__device__ __forceinline__ int b_src(int kt) { return (kt < 4) ? kt : kt - 4; } // hi,hi,lo

// ---------------------------------------------------------------------------
// Kernel 0: fp32 -> f16 hi/lo split (row = [hi|lo], 256 f16) + squared norms
// + init packed argmin keys. One wave per 2 rows; float4 loads, half4 stores.
// ---------------------------------------------------------------------------
__global__ __launch_bounds__(256) void convert_kernel(
    const float* __restrict__ d1, const float* __restrict__ d2,
    _Float16* __restrict__ A2, _Float16* __restrict__ B2,
    float* __restrict__ asq, float* __restrict__ bsq,
    unsigned long long* __restrict__ packed) {
  int gid  = blockIdx.x * 256 + threadIdx.x;
  int wv   = gid >> 6;
  int lane = gid & 63;
  int rowc = 2 * wv + (lane >> 5);
  bool isA = rowc < NB1;
  const float* src = isA ? d1 : d2;
  int row = isA ? rowc : rowc - NB1;
  int k4  = (lane & 31) * 4;

  float4 v = *(const float4*)&src[row * DDIM + k4];
  _Float16 h0 = (_Float16)v.x, h1 = (_Float16)v.y;
  _Float16 h2 = (_Float16)v.z, h3 = (_Float16)v.w;
  half4 hh = {h0, h1, h2, h3};
  half4 ll = {(_Float16)(v.x - (float)h0), (_Float16)(v.y - (float)h1),
              (_Float16)(v.z - (float)h2), (_Float16)(v.w - (float)h3)};

  _Float16* dst = (isA ? A2 : B2) + (size_t)row * KROW;
  *(half4*)&dst[k4]       = hh;
  *(half4*)&dst[128 + k4] = ll;

  float s = v.x * v.x + v.y * v.y + v.z * v.z + v.w * v.w;
  #pragma unroll
  for (int off = 16; off > 0; off >>= 1) s += __shfl_xor(s, off, 64);
  if ((lane & 31) == 0) (isA ? asq : bsq)[row] = s;

  if (gid < NB1) packed[gid] = 0xFFFFFFFFFFFFFFFFull;  // +inf key
}

// ---------------------------------------------------------------------------
// Kernel 1: MFMA GEMM (virtual K=384 f16, fp32 acc) + fused row argmin.
// 256x256 tile, 8 waves (4Mx2N), each wave 2x4 mfma_f32_32x32x16_f16 x 2 ksub.
// Round-3: revert to the round-1 single-barrier/step schedule (the explicit
// per-phase lgkmcnt(0) drain of round-2 destroyed the compiler's counted
// lgkm interleave and regressed 25%); swap MFMA shape 16x16x32 -> 32x32x16
// (2495 vs 2075 TF ubench => per-step MFMA floor -17%, half the MFMA issue
// slots). LDS layout, staging, swizzle, vmcnt ledger identical to round 1:
//  - 4-buffer LDS ring (128 KiB), depth-3 prefetch, vmcnt(8...8,4,0) before
//    the per-step barrier; never drains to 0 mid-loop.
//  - T2 swizzle: 16B cell (row r, chunk q) at slot (q + (r>>1)) & 3; staging
//    fetches the inverse-permuted global chunk (linear global_load_lds dest).
//    32-row frag reads stay uniform over banks (8 accesses/bank).
//  - frag layout 32x32x16: A row = lane&31, k-chunk = ksub*2 + (lane>>5);
//    C/D: col = lane&31, row = (reg&3) + 8*(reg>>2) + 4*(lane>>5).
// ---------------------------------------------------------------------------
__global__ __launch_bounds__(512, 2) void mfma_match_kernel(
    const _Float16* __restrict__ A2, const _Float16* __restrict__ B2,
    const float* __restrict__ bsq, unsigned long long* __restrict__ packed) {
  __shared__ unsigned long long smem[16384];  // 128 KiB: 4 x (A 16KB | B 16KB)
  _Float16* S = (_Float16*)smem;

  const int t    = threadIdx.x;
  const int lane = t & 63;
  const int wid  = t >> 6;           // 0..7
  const int wm   = wid >> 1;         // 0..3 : 64-row band of A
  const int wn   = wid & 1;          // 0..1 : 128-col band of B
  const int r31  = lane & 31;        // frag row within 32-tile
  const int q2   = lane >> 5;        // frag k-group
  const int rsw  = (r31 >> 1) & 3;   // row component of the cell swizzle

  // XCD swizzle: 1024 blocks over 8 XCDs; per-XCD 16(bx) x 8(by) rectangle
  // -> resident set 16 A-panels (2 MB) + 8 B-panels (1 MB) < 4 MB L2.
  const int id  = blockIdx.x;
  const int xcd = id & 7, kk = id >> 3;          // kk 0..127
  const int bx = (xcd & 1) * 16 + (kk & 15);
  const int by = (xcd >> 1) * 8 + (kk >> 4);
  const int row0 = bx * 256, col0 = by * 256;

  // Staging lane geometry: call covers 128 rows; thread t -> row t>>2,
  // LDS slot t&3; global chunk = inverse bank-swizzle (slot - (row>>1)) & 3.
  const int rstg  = t >> 2;
  const int cslot = t & 3;

  float16v acc[2][4];
  #pragma unroll
  for (int mt = 0; mt < 2; ++mt)
    #pragma unroll
    for (int nt = 0; nt < 4; ++nt)
      #pragma unroll
      for (int x = 0; x < 16; ++x) acc[mt][nt][x] = 0.f;

  // Prefetch bsq for the epilogue (drains once in the first vmcnt; harmless).
  const int jc0 = col0 + wn * 128 + r31;
  float bq[4];
  #pragma unroll
  for (int nt = 0; nt < 4; ++nt) bq[nt] = bsq[jc0 + 32 * nt];

  auto stage = [&](int kt, int buf) {
    const int koA = a_src(kt) * 32, koB = b_src(kt) * 32;
    #pragma unroll
    for (int call = 0; call < 2; ++call) {
      const int R  = call * 128 + rstg;
      const int cc = (cslot - (R >> 1)) & 3;
      const _Float16* ga = A2 + (size_t)(row0 + R) * KROW + koA + cc * 8;
      __builtin_amdgcn_global_load_lds((glb_void*)ga,
          (lds_void*)(S + buf * 16384 + call * 4096 + wid * 512), 16, 0, 0);
      const _Float16* gb = B2 + (size_t)(col0 + R) * KROW + koB + cc * 8;
      __builtin_amdgcn_global_load_lds((glb_void*)gb,
          (lds_void*)(S + buf * 16384 + 8192 + call * 4096 + wid * 512), 16, 0, 0);
    }
  };

  auto compute = [&](int buf) {
    const _Float16* Ab = S + buf * 16384;
    const _Float16* Bb = Ab + 8192;
    half8 af[2][2], bf[2][4];
    #pragma unroll
    for (int ks = 0; ks < 2; ++ks) {
      const int sl = ((ks * 2 + q2 + rsw) & 3) * 8;  // swizzled 16B cell
      #pragma unroll
      for (int mt = 0; mt < 2; ++mt)
        af[ks][mt] = *(const half8*)&Ab[(wm * 64 + mt * 32 + r31) * 32 + sl];
      #pragma unroll
      for (int nt = 0; nt < 4; ++nt)
        bf[ks][nt] = *(const half8*)&Bb[(wn * 128 + nt * 32 + r31) * 32 + sl];
    }
    __builtin_amdgcn_s_setprio(1);
    #pragma unroll
    for (int ks = 0; ks < 2; ++ks)
      #pragma unroll
      for (int mt = 0; mt < 2; ++mt)
        #pragma unroll
        for (int nt = 0; nt < 4; ++nt)
          acc[mt][nt] = __builtin_amdgcn_mfma_f32_32x32x16_f16(
              af[ks][mt], bf[ks][nt], acc[mt][nt], 0, 0, 0);
    __builtin_amdgcn_s_setprio(0);
  };

  // Prologue: depth-3 prefetch (12 loads/thread in flight).
  stage(0, 0); stage(1, 1); stage(2, 2);

#define STEP(K, N)                                                    \
  do {                                                                \
    asm volatile("s_waitcnt vmcnt(" #N ")" ::: "memory");             \
    __builtin_amdgcn_s_barrier();                                     \
    asm volatile("" ::: "memory");                                    \
    if constexpr ((K) + 3 < NSTEP) stage((K) + 3, ((K) + 3) & 3);     \
    compute((K) & 3);                                                 \
  } while (0)

  STEP(0, 8);  STEP(1, 8);  STEP(2, 8);  STEP(3, 8);
  STEP(4, 8);  STEP(5, 8);  STEP(6, 8);  STEP(7, 8);
  STEP(8, 8);  STEP(9, 8);  STEP(10, 4); STEP(11, 0);
#undef STEP

  // ---- Epilogue. 32x32 C/D: col = lane&31, row = (reg&3)+8*(reg>>2)+4*q2.
  __syncthreads();  // vmcnt fully drained (STEP 11 waited 0); frag reads done
  #pragma unroll
  for (int mt = 0; mt < 2; ++mt) {
    #pragma unroll
    for (int reg = 0; reg < 16; ++reg) {
      float bv = 1e30f; int bj = 0;
      #pragma unroll
      for (int nt = 0; nt < 4; ++nt) {  // j ascending -> strict < keeps min j
        float val = fmaf(-2.f, acc[mt][nt][reg], bq[nt]);
        if (val < bv) { bv = val; bj = jc0 + 32 * nt; }
      }
      unsigned long long key = packkey(bv, bj);
      unsigned long long oth = __shfl_xor(key, 16, 64);  // fold col ^ 16
      if (oth < key) key = oth;                          // u64 min keeps min j
      if ((lane & 16) == 0) {
        const int mrow =
            wm * 64 + mt * 32 + (reg & 3) + 8 * (reg >> 2) + 4 * q2;
        smem[mrow * 33 + wn * 16 + (lane & 15)] = key;   // pad-33: no 16-way
      }
    }
  }
  __syncthreads();
  if (t < 256) {
    unsigned long long best = ~0ull;
    #pragma unroll
    for (int c = 0; c < 32; ++c) {   // rotated read: spread banks across rows
      unsigned long long kx = smem[t * 33 + ((2 * t + c) & 31)];
      if (kx < best) best = kx;
    }
    atomicMin(&packed[row0 + t], best);  // device-scope; lex (val, idx) min
  }
}

// ---------------------------------------------------------------------------
// Kernel 2: decode packed keys, write outputs.
// ---------------------------------------------------------------------------
__global__ __launch_bounds__(256) void out_kernel(
    const unsigned long long* __restrict__ packed,
    const float* __restrict__ asq, float* __restrict__ out) {
  int r = blockIdx.x * 256 + threadIdx.x;
  unsigned long long best = packed[r];
  unsigned u = (unsigned)(best >> 32);
  u = (u & 0x80000000u) ? (u & 0x7fffffffu) : ~u;   // invert monotone map
  float val  = __uint_as_float(u);
  float dist = sqrtf(fmaxf(asq[r] + val, 0.f));
  int j = (int)(unsigned)(best & 0xffffffffu);
  out[r]               = dist;
  out[NB1 + 2 * r]     = (float)r;
  out[NB1 + 2 * r + 1] = (float)j;
}

extern "C" void kernel_launch(void* const* d_in, const int* in_sizes, int n_in,
                              void* d_out, int out_size, void* d_ws, size_t ws_size,
                              hipStream_t stream) {
  const float* d1 = (const float*)d_in[0];
  const float* d2 = (const float*)d_in[1];
  float* out = (float*)d_out;

  char* w = (char*)d_ws;
  float* asq = (float*)w;                                   // 32 KB
  float* bsq = (float*)(w + 32768);                         // 32 KB
  _Float16* A2 = (_Float16*)(w + 65536);                    // 4 MB
  _Float16* B2 = (_Float16*)(w + 65536 + 4194304);          // 4 MB
  unsigned long long* packed =
      (unsigned long long*)(w + 65536 + 2 * 4194304);       // 64 KB

  convert_kernel<<<(NB1 + NB2) / 8, 256, 0, stream>>>(
      d1, d2, A2, B2, asq, bsq, packed);

  mfma_match_kernel<<<(NB1 / 256) * (NB2 / 256), 512, 0, stream>>>(
      A2, B2, bsq, packed);

  out_kernel<<<NB1 / 256, 256, 0, stream>>>(packed, asq, out);
}

// Round 4
// 122.691 us; speedup vs baseline: 1.1101x; 1.1101x over previous
//
#include <hip/hip_runtime.h>
#include <cstdint>

#define NB1 8192
#define NB2 8192
#define DDIM 128
#define KROW 256           // stored row: [hi(128) | lo(128)] f16
#define NSTEP 12           // virtual K = 384 (hi*hi + lo*hi + hi*lo), 32 f16/step

using half8   = __attribute__((ext_vector_type(8))) _Float16;
using half4   = __attribute__((ext_vector_type(4))) _Float16;
using float4v = __attribute__((ext_vector_type(4))) float;

typedef __attribute__((address_space(3))) void       lds_void;
typedef const __attribute__((address_space(1))) void glb_void;

__device__ inline unsigned long long packkey(float v, int j) {
  unsigned u = __float_as_uint(v);
  u = (u & 0x80000000u) ? ~u : (u | 0x80000000u);  // monotone float->uint
  return ((unsigned long long)u << 32) | (unsigned)j;
}

// virtual kt -> source 32-f16 chunk index within the [hi|lo] row
__device__ __forceinline__ int a_src(int kt) { return (kt < 8) ? kt : kt - 8; } // hi,lo,hi
__device__ __forceinline__ int b_src(int kt) { return (kt < 4) ? kt : kt - 4; } // hi,hi,lo

// ---------------------------------------------------------------------------
// Kernel 0: fp32 -> f16 hi/lo split (row = [hi|lo], 256 f16) + squared norms
// + init packed argmin keys. One wave per 2 rows; float4 loads, half4 stores.
// ---------------------------------------------------------------------------
__global__ __launch_bounds__(256) void convert_kernel(
    const float* __restrict__ d1, const float* __restrict__ d2,
    _Float16* __restrict__ A2, _Float16* __restrict__ B2,
    float* __restrict__ asq, float* __restrict__ bsq,
    unsigned long long* __restrict__ packed) {
  int gid  = blockIdx.x * 256 + threadIdx.x;
  int wv   = gid >> 6;
  int lane = gid & 63;
  int rowc = 2 * wv + (lane >> 5);
  bool isA = rowc < NB1;
  const float* src = isA ? d1 : d2;
  int row = isA ? rowc : rowc - NB1;
  int k4  = (lane & 31) * 4;

  float4 v = *(const float4*)&src[row * DDIM + k4];
  _Float16 h0 = (_Float16)v.x, h1 = (_Float16)v.y;
  _Float16 h2 = (_Float16)v.z, h3 = (_Float16)v.w;
  half4 hh = {h0, h1, h2, h3};
  half4 ll = {(_Float16)(v.x - (float)h0), (_Float16)(v.y - (float)h1),
              (_Float16)(v.z - (float)h2), (_Float16)(v.w - (float)h3)};

  _Float16* dst = (isA ? A2 : B2) + (size_t)row * KROW;
  *(half4*)&dst[k4]       = hh;
  *(half4*)&dst[128 + k4] = ll;

  float s = v.x * v.x + v.y * v.y + v.z * v.z + v.w * v.w;
  #pragma unroll
  for (int off = 16; off > 0; off >>= 1) s += __shfl_xor(s, off, 64);
  if ((lane & 31) == 0) (isA ? asq : bsq)[row] = s;

  if (gid < NB1) packed[gid] = 0xFFFFFFFFFFFFFFFFull;  // +inf key
}

// ---------------------------------------------------------------------------
// Kernel 1: MFMA GEMM (virtual K=384 f16, fp32 acc) + fused row argmin.
// Round-4: 256x128 tile, 8 waves (4Mx2N), 4x4 mfma_f32_16x16x32_f16 per wave.
// LDS ring of 3 x 24 KB = 72 KB -> 2 blocks/CU (16 waves, 4/SIMD): when one
// block sits at its per-step barrier/vmcnt, the co-resident block's waves
// feed the MFMA pipe (m97/m114 cross-block overlap — the mechanism rounds
// 2-3 failed to get intra-block). Schedule per step is round-1's verified
// single-barrier form with counted vmcnt:
//   vmcnt(3) [drain stage k; stage k+1 (3 loads) stays in flight]
//   s_barrier; stage(k+2) -> buf (k+2)%3 (retired: its reads finished
//   before this barrier); 8 ds_read_b128; setprio1; 16 MFMA; setprio0.
// Tail: vmcnt 3,...,3,0. Frag reads use the round-1 16-row/lane-group
// pattern + chunk-rotation swizzle (verified SQ_LDS_BANK_CONFLICT = 0);
// the 32-row pattern of round 3 conflicted 8-way — do not reintroduce.
// ---------------------------------------------------------------------------
__global__ __launch_bounds__(512, 4) void mfma_match_kernel(
    const _Float16* __restrict__ A2, const _Float16* __restrict__ B2,
    const float* __restrict__ bsq, unsigned long long* __restrict__ packed) {
  __shared__ unsigned long long smem[9216];  // 73728 B: 3 x (A 16KB | B 8KB)
  _Float16* S = (_Float16*)smem;             // buffer b at S + b*12288

  const int t    = threadIdx.x;
  const int lane = t & 63;
  const int wid  = t >> 6;           // 0..7
  const int wm   = wid >> 1;         // 0..3 : 64-row band of A (tile M=256)
  const int wn   = wid & 1;          // 0..1 : 64-col band of B (tile N=128)
  const int lx   = lane & 15, q = lane >> 4;

  // XCD swizzle: 2048 blocks over 8 XCDs; per-XCD 16(bx) x 16(by) rectangle
  // -> resident set 16 A-panels (2 MB) + 16 B-panels (1 MB) < 4 MB L2.
  const int id  = blockIdx.x;
  const int xcd = id & 7, kk = id >> 3;          // kk 0..255
  const int bx = (xcd & 1) * 16 + (kk & 15);     // 0..31  (M tiles of 256)
  const int by = (xcd >> 1) * 16 + (kk >> 4);    // 0..63  (N tiles of 128)
  const int row0 = bx * 256, col0 = by * 128;

  // Staging lane geometry: one call covers 128 rows; thread t -> row t>>2,
  // LDS slot t&3; global chunk = inverse bank-swizzle (slot - (row>>1)) & 3.
  const int rstg  = t >> 2;
  const int cslot = t & 3;

  float4v acc[4][4];
  #pragma unroll
  for (int r = 0; r < 4; ++r)
    #pragma unroll
    for (int c = 0; c < 4; ++c) acc[r][c] = (float4v){0.f, 0.f, 0.f, 0.f};

  // Prefetch bsq + column ids for the epilogue.
  float bq[4]; int jc[4];
  #pragma unroll
  for (int c = 0; c < 4; ++c) {
    jc[c] = col0 + wn * 64 + 16 * c + lx;
    bq[c] = bsq[jc[c]];
  }

  // 3 gloads/thread/stage: A rows 0-127, A rows 128-255, B rows 0-127.
  auto stage = [&](int kt, int buf) {
    const int koA = a_src(kt) * 32, koB = b_src(kt) * 32;
    const int cc0 = (cslot - (rstg >> 1)) & 3;   // (rstg+128)>>1 same mod 4
    #pragma unroll
    for (int call = 0; call < 2; ++call) {
      const _Float16* ga =
          A2 + (size_t)(row0 + call * 128 + rstg) * KROW + koA + cc0 * 8;
      __builtin_amdgcn_global_load_lds((glb_void*)ga,
          (lds_void*)(S + buf * 12288 + call * 4096 + wid * 512), 16, 0, 0);
    }
    const _Float16* gb = B2 + (size_t)(col0 + rstg) * KROW + koB + cc0 * 8;
    __builtin_amdgcn_global_load_lds((glb_void*)gb,
        (lds_void*)(S + buf * 12288 + 8192 + wid * 512), 16, 0, 0);
  };

  const int sw = ((q + (lx >> 1)) & 3) * 8;   // bank-swizzled chunk offset

  auto compute = [&](int buf) {
    const _Float16* Ab = S + buf * 12288;
    const _Float16* Bb = Ab + 8192;
    half8 af[4], bf[4];
    #pragma unroll
    for (int r = 0; r < 4; ++r)
      af[r] = *(const half8*)&Ab[(wm * 64 + 16 * r + lx) * 32 + sw];
    #pragma unroll
    for (int c = 0; c < 4; ++c)
      bf[c] = *(const half8*)&Bb[(wn * 64 + 16 * c + lx) * 32 + sw];
    __builtin_amdgcn_s_setprio(1);
    #pragma unroll
    for (int r = 0; r < 4; ++r)
      #pragma unroll
      for (int c = 0; c < 4; ++c)
        acc[r][c] = __builtin_amdgcn_mfma_f32_16x16x32_f16(
            af[r], bf[c], acc[r][c], 0, 0, 0);
    __builtin_amdgcn_s_setprio(0);
  };

  // Prologue: depth-2 prefetch (6 loads/thread in flight).
  stage(0, 0); stage(1, 1);

#define STEP(K, N)                                                    \
  do {                                                                \
    asm volatile("s_waitcnt vmcnt(" #N ")" ::: "memory");             \
    __builtin_amdgcn_s_barrier();                                     \
    asm volatile("" ::: "memory");                                    \
    if constexpr ((K) + 2 < NSTEP) stage((K) + 2, ((K) + 2) % 3);     \
    compute((K) % 3);                                                 \
  } while (0)

  STEP(0, 3);  STEP(1, 3);  STEP(2, 3);  STEP(3, 3);
  STEP(4, 3);  STEP(5, 3);  STEP(6, 3);  STEP(7, 3);
  STEP(8, 3);  STEP(9, 3);  STEP(10, 3); STEP(11, 0);
#undef STEP

  // ---- Epilogue. C/D layout: col = lane&15, row = q*4 + reg. ----
  __syncthreads();  // vmcnt drained (STEP 11 waited 0); all frag reads done
  #pragma unroll
  for (int r = 0; r < 4; ++r) {
    #pragma unroll
    for (int reg = 0; reg < 4; ++reg) {
      float bv = 1e30f; int bj = 0;
      #pragma unroll
      for (int c = 0; c < 4; ++c) {  // jc ascending -> strict < keeps min j
        float val = fmaf(-2.f, acc[r][c][reg], bq[c]);
        if (val < bv) { bv = val; bj = jc[c]; }
      }
      const int mrow = wm * 64 + 16 * r + 4 * q + reg;
      smem[mrow * 33 + wn * 16 + lx] = packkey(bv, bj);  // pad-33: no 16-way
    }
  }
  __syncthreads();
  if (t < 256) {
    unsigned long long best = ~0ull;
    #pragma unroll
    for (int c = 0; c < 32; ++c) {   // rotated read: spread banks across rows
      unsigned long long kx = smem[t * 33 + ((2 * t + c) & 31)];
      if (kx < best) best = kx;
    }
    atomicMin(&packed[row0 + t], best);  // device-scope; lex (val, idx) min
  }
}

// ---------------------------------------------------------------------------
// Kernel 2: decode packed keys, write outputs.
// ---------------------------------------------------------------------------
__global__ __launch_bounds__(256) void out_kernel(
    const unsigned long long* __restrict__ packed,
    const float* __restrict__ asq, float* __restrict__ out) {
  int r = blockIdx.x * 256 + threadIdx.x;
  unsigned long long best = packed[r];
  unsigned u = (unsigned)(best >> 32);
  u = (u & 0x80000000u) ? (u & 0x7fffffffu) : ~u;   // invert monotone map
  float val  = __uint_as_float(u);
  float dist = sqrtf(fmaxf(asq[r] + val, 0.f));
  int j = (int)(unsigned)(best & 0xffffffffu);
  out[r]               = dist;
  out[NB1 + 2 * r]     = (float)r;
  out[NB1 + 2 * r + 1] = (float)j;
}

extern "C" void kernel_launch(void* const* d_in, const int* in_sizes, int n_in,
                              void* d_out, int out_size, void* d_ws, size_t ws_size,
                              hipStream_t stream) {
  const float* d1 = (const float*)d_in[0];
  const float* d2 = (const float*)d_in[1];
  float* out = (float*)d_out;

  char* w = (char*)d_ws;
  float* asq = (float*)w;                                   // 32 KB
  float* bsq = (float*)(w + 32768);                         // 32 KB
  _Float16* A2 = (_Float16*)(w + 65536);                    // 4 MB
  _Float16* B2 = (_Float16*)(w + 65536 + 4194304);          // 4 MB
  unsigned long long* packed =
      (unsigned long long*)(w + 65536 + 2 * 4194304);       // 64 KB

  convert_kernel<<<(NB1 + NB2) / 8, 256, 0, stream>>>(
      d1, d2, A2, B2, asq, bsq, packed);

  mfma_match_kernel<<<(NB1 / 256) * (NB2 / 128), 512, 0, stream>>>(
      A2, B2, bsq, packed);

  out_kernel<<<NB1 / 256, 256, 0, stream>>>(packed, asq, out);
}